// Round 13
// baseline (131.426 us; speedup 1.0000x reference)
//
#include <hip/hip_runtime.h>

typedef unsigned short ushort;
typedef __attribute__((ext_vector_type(4)))  float  f32x4;
typedef __attribute__((ext_vector_type(16))) float  f32x16;
typedef __attribute__((ext_vector_type(8)))  short  s16x8;
typedef __attribute__((ext_vector_type(4)))  ushort u16x4;
typedef __attribute__((ext_vector_type(4)))  unsigned u32x4;

#define MFMA16(a, b, c) __builtin_amdgcn_mfma_f32_16x16x32_bf16((a), (b), (c), 0, 0, 0)
#define MFMA32(a, b, c) __builtin_amdgcn_mfma_f32_32x32x16_bf16((a), (b), (c), 0, 0, 0)

__device__ __forceinline__ ushort f2bf(float f) {
    unsigned u = __builtin_bit_cast(unsigned, f);
    u = (u + 0x7FFF + ((u >> 16) & 1)) >> 16;   // RNE
    return (ushort)u;
}

__device__ __forceinline__ unsigned cvtpk_bf16(float lo, float hi) {
    unsigned r;
    asm("v_cvt_pk_bf16_f32 %0, %1, %2" : "=v"(r) : "v"(lo), "v"(hi));
    return r;
}
// After the swap: a = [a_lo31 | b_lo31], b = [a_hi31 | b_hi31].
// Only safe when a and b are DISTINCT SSA values (regalloc coalescing hazard).
__device__ __forceinline__ void plswap(unsigned& a, unsigned& b) {
    asm volatile("v_permlane32_swap_b32 %0, %1" : "+v"(a), "+v"(b));
}
// Pair (lane ^ 32) reductions via permlane32_swap (pure VALU, no DS op).
__device__ __forceinline__ float pairmax(float x) {
    unsigned a = __builtin_bit_cast(unsigned, x), b;
    asm("v_mov_b32 %0, %1" : "=v"(b) : "v"(a));
    plswap(a, b);
    return fmaxf(__builtin_bit_cast(float, a), __builtin_bit_cast(float, b));
}
__device__ __forceinline__ float pairsum(float x) {
    unsigned a = __builtin_bit_cast(unsigned, x), b;
    asm("v_mov_b32 %0, %1" : "=v"(b) : "v"(a));
    plswap(a, b);
    return __builtin_bit_cast(float, a) + __builtin_bit_cast(float, b);
}
// Raw 2^x. exp() folded to exp2 via Q pre-scale by log2(e).
__device__ __forceinline__ float fast_exp2(float x) {
    float r;
    asm("v_exp_f32 %0, %1" : "=v"(r) : "v"(x));
    return r;
}

__device__ __forceinline__ void gload_lds16(const ushort* g, ushort* l) {
    __builtin_amdgcn_global_load_lds(
        (const __attribute__((address_space(1))) void*)g,
        (__attribute__((address_space(3))) void*)l, 16, 0, 0);
}

// ---------------------------------------------------------------------------
// fp32 -> bf16 conversion for all three inputs in ONE dispatch.
// ---------------------------------------------------------------------------
__global__ __launch_bounds__(256) void cvt_all(
    const float* __restrict__ x, const float* __restrict__ wq,
    const float* __restrict__ wp, ushort* __restrict__ out,
    int n4x, int n4q, int n4p)
{
    int i = blockIdx.x * blockDim.x + threadIdx.x;
    const int stride = gridDim.x * blockDim.x;
    const int total = n4x + n4q + n4p;
    for (; i < total; i += stride) {
        float4 v;
        if (i < n4x)            v = ((const float4*)x)[i];
        else if (i < n4x + n4q) v = ((const float4*)wq)[i - n4x];
        else                    v = ((const float4*)wp)[i - n4x - n4q];
        u16x4 o;
        o[0] = f2bf(v.x); o[1] = f2bf(v.y); o[2] = f2bf(v.z); o[3] = f2bf(v.w);
        ((u16x4*)out)[i] = o;
    }
}

// ---------------------------------------------------------------------------
// Kernel 1: QKV GEMM, 256x256 tile / 8 waves / 8-phase counted-vmcnt schedule
// (m201-style template, slot-XOR swizzle).  C = X[8192x768] * W[2304x768]^T.
// 512 threads = 8 waves (2M x 4N); per-wave output 128x64 = acc[8][4].
// LDS 128KB: A,B each 2 buffers x [256 rows][64 k] bf16 (row = 128B).
// Swizzle: 16B-slot p at row r holds global slot p ^ (r&7) (pre-swizzled
// source for gload_lds, XOR on ds_read).
// Per iteration (2 K-tiles: k0=2j in buf0, k1=2j+1 in buf1), 8 phases:
// each = {ds_read new frags | stage 1 half-tile} -> barrier -> 16 MFMA ->
// [vmcnt(4) at ph4/ph8] -> barrier.  Stage order (iter j):
//  ph1 A0(2j+1)->b1  ph2 A1(2j+1)->b1  ph3 B0(2j+2)->b0  ph4 B1(2j+2)->b0
//  ph5 A0(2j+2)->b0  ph6 A1(2j+2)->b0  ph7 B0(2j+3)->b1  ph8 B1(2j+3)->b1
// RAW: vmcnt(4) at ph4/8 leaves exactly the last 2 half-tiles outstanding;
// WAR: every stage lands >=1 barrier after the last read of its region.
// Tail: iter 5 ph4 uses vmcnt(0) (A(11) staged same-iter ph1-2).
// Epilogue scatters q (pre-scaled by SCALE*log2e), k, vT as before.
// ---------------------------------------------------------------------------
__global__ __launch_bounds__(512, 2) void qkv_gemm256(
    const ushort* __restrict__ X, const ushort* __restrict__ W,
    ushort* __restrict__ qb, ushort* __restrict__ kb, ushort* __restrict__ vb)
{
    __shared__ __align__(16) ushort LA[2][16384];   // 2 x 32KB
    __shared__ __align__(16) ushort LB[2][16384];   // 2 x 32KB

    const int t  = threadIdx.x;
    const int l  = t & 63;
    const int w  = t >> 6;
    const int lr = l & 15, lg = l >> 4;
    const int wm = w >> 2, wn = w & 3;
    const int br = blockIdx.x, bc = blockIdx.y;
    const int fx = (lr & 7) << 4;

    f32x4 acc[8][4];
#pragma unroll
    for (int m = 0; m < 8; m++)
#pragma unroll
        for (int n = 0; n < 4; n++) acc[m][n] = (f32x4){0.f, 0.f, 0.f, 0.f};

    // staging source bases: thread t covers row (t>>3) (+64 for 2nd gload,
    // +128*h for half h), pre-swizzled slot ss = (t&7) ^ ((t>>3)&7).
    const int ss = (t & 7) ^ ((t >> 3) & 7);
    const ushort* aRow = X + (size_t)(br * 256 + (t >> 3)) * 768 + ss * 8;
    const ushort* bRow = W + (size_t)(bc * 256 + (t >> 3)) * 768 + ss * 8;

    auto stA_raw = [&](int kt, int h, int buf) {
        const ushort* s = aRow + (size_t)(h * 128) * 768 + kt * 64;
        gload_lds16(s,            &LA[buf][h * 8192 + t * 8]);
        gload_lds16(s + 64 * 768, &LA[buf][h * 8192 + 4096 + t * 8]);
    };
    auto stB_raw = [&](int kt, int h, int buf) {
        const ushort* s = bRow + (size_t)(h * 128) * 768 + kt * 64;
        gload_lds16(s,            &LB[buf][h * 8192 + t * 8]);
        gload_lds16(s + 64 * 768, &LB[buf][h * 8192 + 4096 + t * 8]);
    };
    auto stA = [&](int kt, int h, int buf) {
        if ((unsigned)(kt - 2) < 10u) stA_raw(kt, h, buf);
    };
    auto stB = [&](int kt, int h, int buf) {
        if ((unsigned)(kt - 2) < 10u) stB_raw(kt, h, buf);
    };

    s16x8 fa[4][2], fb0[2][2], fb1[2][2];

#define RD_A(BUF, MI0)                                                       \
    _Pragma("unroll") for (int i_ = 0; i_ < 4; i_++)                         \
    _Pragma("unroll") for (int kk = 0; kk < 2; kk++)                         \
        fa[i_][kk] = *(const s16x8*)((const char*)&LA[BUF][0] +              \
            (wm * 128 + (MI0 + i_) * 16 + lr) * 128 + ((kk * 64 + lg * 16) ^ fx));
#define RD_B(BUF, NI0, FB)                                                   \
    _Pragma("unroll") for (int n_ = 0; n_ < 2; n_++)                         \
    _Pragma("unroll") for (int kk = 0; kk < 2; kk++)                         \
        FB[n_][kk] = *(const s16x8*)((const char*)&LB[BUF][0] +              \
            (wn * 64 + (NI0 + n_) * 16 + lr) * 128 + ((kk * 64 + lg * 16) ^ fx));
#define MFMA_Q(MI0, NI0, FB)                                                 \
    __builtin_amdgcn_s_setprio(1);                                           \
    _Pragma("unroll") for (int i_ = 0; i_ < 4; i_++)                         \
    _Pragma("unroll") for (int n_ = 0; n_ < 2; n_++)                         \
    _Pragma("unroll") for (int kk = 0; kk < 2; kk++)                         \
        acc[MI0 + i_][NI0 + n_] =                                            \
            MFMA16(fa[i_][kk], FB[n_][kk], acc[MI0 + i_][NI0 + n_]);         \
    __builtin_amdgcn_s_setprio(0);
#define BAR() __builtin_amdgcn_s_barrier()

    // prologue: K-tiles 0 (buf0) and 1 (buf1) fully staged
    stA_raw(0, 0, 0); stA_raw(0, 1, 0); stB_raw(0, 0, 0); stB_raw(0, 1, 0);
    stA_raw(1, 0, 1); stA_raw(1, 1, 1); stB_raw(1, 0, 1); stB_raw(1, 1, 1);
    asm volatile("s_waitcnt vmcnt(0)" ::: "memory");
    BAR();

    for (int j = 0; j < 6; ++j) {
        const int k1 = 2 * j + 1, k2 = 2 * j + 2, k3 = 2 * j + 3;
        // ---- K-tile 2j (buf0): phases 1-4 ----
        RD_A(0, 0); RD_B(0, 0, fb0);
        stA(k1, 0, 1);
        BAR(); MFMA_Q(0, 0, fb0); BAR();

        RD_B(0, 2, fb1);
        stA(k1, 1, 1);
        BAR(); MFMA_Q(0, 2, fb1); BAR();

        RD_A(0, 4);
        stB(k2, 0, 0);
        BAR(); MFMA_Q(4, 0, fb0); BAR();

        stB(k2, 1, 0);
        BAR(); MFMA_Q(4, 2, fb1);
        if (j == 5) { asm volatile("s_waitcnt vmcnt(0)" ::: "memory"); }
        else        { asm volatile("s_waitcnt vmcnt(4)" ::: "memory"); }
        BAR();

        // ---- K-tile 2j+1 (buf1): phases 5-8 ----
        RD_A(1, 0); RD_B(1, 0, fb0);
        stA(k2, 0, 0);
        BAR(); MFMA_Q(0, 0, fb0); BAR();

        RD_B(1, 2, fb1);
        stA(k2, 1, 0);
        BAR(); MFMA_Q(0, 2, fb1); BAR();

        RD_A(1, 4);
        stB(k3, 0, 1);
        BAR(); MFMA_Q(4, 0, fb0); BAR();

        stB(k3, 1, 1);
        BAR(); MFMA_Q(4, 2, fb1);
        asm volatile("s_waitcnt vmcnt(4)" ::: "memory");
        BAR();
    }
#undef RD_A
#undef RD_B
#undef MFMA_Q
#undef BAR

    // ---- epilogue: scatter q (scaled), k, vT ----
    const int p = bc / 3;                       // 0:q 1:k 2:v (bc 0-8)
    const int mrow0 = br * 256 + wm * 128 + lg * 4;
    const int ecol0 = (bc - p * 3) * 256 + wn * 64 + lr;
    const float QSCALE = 0.125f * 1.44269504088896f;  // SCALE * log2(e)

#pragma unroll
    for (int n = 0; n < 4; n++) {
        const int rem = ecol0 + n * 16;         // 0..767
        const int h   = rem >> 6;
        const int hd  = rem & 63;
#pragma unroll
        for (int m = 0; m < 8; m++) {
            const int mr = mrow0 + m * 16;
            const int b  = mr >> 10;
            const int nn = mr & 1023;
            const f32x4 v = acc[m][n];
            const int bh = b * 12 + h;
            if (p == 0) {
                ushort* dst = qb + (bh * 1024 + nn) * 64 + hd;
#pragma unroll
                for (int r = 0; r < 4; r++) dst[r * 64] = f2bf(v[r] * QSCALE);
            } else if (p == 1) {
                ushort* dst = kb + (bh * 1024 + nn) * 64 + hd;
#pragma unroll
                for (int r = 0; r < 4; r++) dst[r * 64] = f2bf(v[r]);
            } else {
                u16x4 pk;
                pk[0] = f2bf(v[0]); pk[1] = f2bf(v[1]);
                pk[2] = f2bf(v[2]); pk[3] = f2bf(v[3]);
                *(u16x4*)(vb + (bh * 64 + hd) * 1024 + nn) = pk;
            }
        }
    }
}

// ---------------------------------------------------------------------------
// 128x128 tile GEMM mainloop (3-buffer / 2-deep prefetch / counted vmcnt,
// slot-XOR swizzle) — retained for proj_gemm.
// ---------------------------------------------------------------------------
__device__ __forceinline__ void gemm128_mainloop(
    const ushort* __restrict__ A, const ushort* __restrict__ B, int K,
    int row0, int col0, ushort* As, ushort* Bs, f32x4 acc[4][4])
{
    const int t  = threadIdx.x;
    const int l  = t & 63;
    const int w  = t >> 6;
    const int lr = l & 15, lg = l >> 4;
    const int wm = w >> 1, wn = w & 1;

#pragma unroll
    for (int m = 0; m < 4; m++)
#pragma unroll
        for (int n = 0; n < 4; n++) acc[m][n] = (f32x4){0.f, 0.f, 0.f, 0.f};

    const int slot = (t & 3) ^ ((t >> 3) & 3);
    const ushort* ga0 = A + (row0 + (t >> 2)) * K + slot * 8;
    const ushort* gb0 = B + (col0 + (t >> 2)) * K + slot * 8;
    const int rowsz = 64 * K;
    ushort* la0 = As + t * 8;
    ushort* lb0 = Bs + t * 8;

    auto STAGE = [&](int kt, int buf) {
        const int k0  = kt * 32;
        const int off = buf * 4096;
        gload_lds16(ga0 + k0,         la0 + off);
        gload_lds16(ga0 + rowsz + k0, la0 + off + 2048);
        gload_lds16(gb0 + k0,         lb0 + off);
        gload_lds16(gb0 + rowsz + k0, lb0 + off + 2048);
    };
    const int sx = (lg ^ ((lr >> 1) & 3)) * 8;
    auto COMPUTE = [&](int buf) {
        const ushort* Ab = As + buf * 4096;
        const ushort* Bb = Bs + buf * 4096;
        s16x8 af[4], bfr[4];
#pragma unroll
        for (int m = 0; m < 4; m++)
            af[m] = *(const s16x8*)&Ab[(wm * 64 + m * 16 + lr) * 32 + sx];
#pragma unroll
        for (int n = 0; n < 4; n++)
            bfr[n] = *(const s16x8*)&Bb[(wn * 64 + n * 16 + lr) * 32 + sx];
        __builtin_amdgcn_s_setprio(1);
#pragma unroll
        for (int m = 0; m < 4; m++)
#pragma unroll
            for (int n = 0; n < 4; n++)
                acc[m][n] = MFMA16(af[m], bfr[n], acc[m][n]);
        __builtin_amdgcn_s_setprio(0);
    };

    const int nt = K >> 5;          // 24; must be divisible by 3
    STAGE(0, 0);
    STAGE(1, 1);
    asm volatile("s_waitcnt vmcnt(4)" ::: "memory");
    __builtin_amdgcn_s_barrier();

#define GSTEP(IT, CBUF, SBUF)                                          \
    {                                                                  \
        const int sk = (IT) + 2;                                       \
        const bool st = sk < nt;                                       \
        if (st) STAGE(sk, SBUF);                                       \
        COMPUTE(CBUF);                                                 \
        if (st) { asm volatile("s_waitcnt vmcnt(4)" ::: "memory"); }   \
        else    { asm volatile("s_waitcnt vmcnt(0)" ::: "memory"); }   \
        __builtin_amdgcn_s_barrier();                                  \
    }

    for (int base = 0; base < nt; base += 3) {
        GSTEP(base,     0, 2);
        GSTEP(base + 1, 1, 0);
        GSTEP(base + 2, 2, 1);
    }
#undef GSTEP
}

// ---------------------------------------------------------------------------
// Kernel 2: flash attention (R11 version, verified 44us). 32x32 swapped-QK,
// KVBLK=32; LDS-staged K/V (double-buffered, source-side XOR swizzle);
// softmax fully in-register; pair reductions via permlane32_swap.
// grid (96 bh, 8 qt), block 256 = 4 waves.
// ---------------------------------------------------------------------------
__global__ __launch_bounds__(256) void attn_kernel(
    const ushort* __restrict__ qb, const ushort* __restrict__ kb,
    const ushort* __restrict__ vb, ushort* __restrict__ ao)
{
    __shared__ __align__(16) ushort KV[2][4096];   // [buf][K 2048 | V 2048] = 16KB
    const int bh = blockIdx.x, qt = blockIdx.y;
    const int b = bh / 12, h = bh - b * 12;
    const int t = threadIdx.x, l = t & 63, w = t >> 6;
    const int lq = l & 31, hi = l >> 5;
    const int qr0 = qt * 128 + w * 32;

    // ---- staging source addresses (pre-swizzled) ----
    const int l3 = l >> 3, l7 = l & 7;
    const int ku = w * 8 + l3;                      // LDS row this lane fills
    const int pfv = l7 ^ l3;                        // swizzled 16B slot index
    const char* ksrc = (const char*)kb + (size_t)(bh * 1024 + ku) * 128
                     + ((l7 ^ l3) << 4);            // + kv0*128 per iter
    const char* vsrc = (const char*)vb + (size_t)(bh * 64 + ku + 32 * ((pfv >> 2) & 1)) * 2048
                     + ((pfv & 3) << 4);            // + kv0*2 per iter
    ushort* kdst = &KV[0][0]    + w * 512 + l * 8;  // uniform base + lane*16B
    ushort* vdst = &KV[0][2048] + w * 512 + l * 8;

    // ---- Q fragments (B-operand): col=q=lq, k=d-slice s*16 + hi*8 ----
    const ushort* qlane = qb + (bh * 1024 + qr0 + lq) * 64 + hi * 8;
    s16x8 qf[4];
#pragma unroll
    for (int s = 0; s < 4; s++) qf[s] = *(const s16x8*)(qlane + s * 16);

    float m = -__builtin_inff();
    float lsum = 0.f;
    f32x16 o0 = {}, o1 = {};

    // prologue: stage tile 0 into buf 0
    gload_lds16((const ushort*)ksrc, kdst);
    gload_lds16((const ushort*)vsrc, vdst);
    __syncthreads();

    const int fx = (lq & 7) << 4;                   // read-side swizzle
    for (int it = 0; it < 32; ++it) {
        const int cur = it & 1;
        // ---- prefetch next tile into the other buffer ----
        if (it < 31) {
            const int kvn = (it + 1) * 32;
            gload_lds16((const ushort*)(ksrc + kvn * 128), kdst + (cur ^ 1) * 4096);
            gload_lds16((const ushort*)(vsrc + kvn * 2),   vdst + (cur ^ 1) * 4096);
        }
        const char* Kb = (const char*)&KV[cur][0];
        const char* Vb = (const char*)&KV[cur][2048];

        // ---- K fragments (A-operand): row kv=lq, d-slice s*16+hi*8 ----
        s16x8 kf[4];
#pragma unroll
        for (int s = 0; s < 4; s++)
            kf[s] = *(const s16x8*)(Kb + lq * 128 + ((hi * 16 + s * 32) ^ fx));

        f32x16 sa = {};
        __builtin_amdgcn_s_setprio(1);
#pragma unroll
        for (int s = 0; s < 4; s++) sa = MFMA32(kf[s], qf[s], sa);
        __builtin_amdgcn_s_setprio(0);

        // ---- in-register online softmax (16 k/lane, pair lane has rest) ----
        float g0 = fmaxf(fmaxf(sa[0],  sa[1]),  sa[2]);
        float g1 = fmaxf(fmaxf(sa[3],  sa[4]),  sa[5]);
        float g2 = fmaxf(fmaxf(sa[6],  sa[7]),  sa[8]);
        float g3 = fmaxf(fmaxf(sa[9],  sa[10]), sa[11]);
        float g4 = fmaxf(fmaxf(sa[12], sa[13]), sa[14]);
        float h0 = fmaxf(fmaxf(g0, g1), g2);
        float h1 = fmaxf(fmaxf(g3, g4), sa[15]);
        const float mx = pairmax(fmaxf(h0, h1));

        if (!__all(mx <= m + 8.f)) {          // defer-max (T13), log2 units
            const float mn = fmaxf(m, mx);
            const float fac = fast_exp2(m - mn);
            m = mn;
            lsum *= fac;
#pragma unroll
            for (int r = 0; r < 16; r++) { o0[r] *= fac; o1[r] *= fac; }
        }

        float p[16];
#pragma unroll
        for (int r = 0; r < 16; r++) p[r] = fast_exp2(sa[r] - m);
        float ts[8];
#pragma unroll
        for (int r = 0; r < 8; r++) ts[r] = p[r] + p[r + 8];
#pragma unroll
        for (int s = 4; s; s >>= 1)
#pragma unroll
            for (int r = 0; r < s; r++) ts[r] += ts[r + s];
        lsum += pairsum(ts[0]);

        // ---- pack P^T into PV B-fragments (cvt_pk + permlane32_swap) ----
        s16x8 pfr[2];
#pragma unroll
        for (int slot = 0; slot < 2; slot++) {
            const int r0 = slot * 8;
            unsigned a0 = cvtpk_bf16(p[r0 + 0], p[r0 + 1]);
            unsigned a1 = cvtpk_bf16(p[r0 + 4], p[r0 + 5]);
            plswap(a0, a1);
            unsigned b0 = cvtpk_bf16(p[r0 + 2], p[r0 + 3]);
            unsigned b1 = cvtpk_bf16(p[r0 + 6], p[r0 + 7]);
            plswap(b0, b1);
            const u32x4 u = {a0, b0, a1, b1};
            pfr[slot] = __builtin_bit_cast(s16x8, u);
        }

        // ---- V fragments + PV: O^T += V^T * P^T ----
        s16x8 vf[2][2];   // [half d0/d32][k-slot]
#pragma unroll
        for (int half = 0; half < 2; half++)
#pragma unroll
            for (int s = 0; s < 2; s++)
                vf[half][s] = *(const s16x8*)(Vb + lq * 128 + ((half * 64 + hi * 16 + s * 32) ^ fx));
        __builtin_amdgcn_s_setprio(1);
        o0 = MFMA32(vf[0][0], pfr[0], o0);
        o1 = MFMA32(vf[1][0], pfr[0], o1);
        o0 = MFMA32(vf[0][1], pfr[1], o0);
        o1 = MFMA32(vf[1][1], pfr[1], o1);
        __builtin_amdgcn_s_setprio(0);

        __syncthreads();   // drains prefetch (vmcnt) + all reads of cur buf
    }

    // ---- epilogue: out[b][q][h*64+d] = O^T[d][q] / lsum ----
    const float inv = 1.f / lsum;
    ushort* op = ao + (b * 1024 + qr0 + lq) * 768 + h * 64 + 4 * hi;
#pragma unroll
    for (int i = 0; i < 4; i++) {
        u16x4 pk0, pk1;
#pragma unroll
        for (int j = 0; j < 4; j++) {
            pk0[j] = f2bf(o0[4 * i + j] * inv);
            pk1[j] = f2bf(o1[4 * i + j] * inv);
        }
        *(u16x4*)(op + 8 * i)      = pk0;   // d = 8i+4hi + 0..3
        *(u16x4*)(op + 32 + 8 * i) = pk1;   // d = 32 + 8i+4hi + 0..3
    }
}

// ---------------------------------------------------------------------------
// Kernel 3: out = attn_out @ proj_w^T + proj_b (fp32 out). grid (64, 6).
// ---------------------------------------------------------------------------
__global__ __launch_bounds__(256) void proj_gemm(
    const ushort* __restrict__ A, const ushort* __restrict__ W,
    const float* __restrict__ bias, float* __restrict__ out)
{
    __shared__ __align__(16) ushort As[3 * 128 * 32];
    __shared__ __align__(16) ushort Bs[3 * 128 * 32];
    f32x4 acc[4][4];
    const int br = blockIdx.x, bc = blockIdx.y;
    gemm128_mainloop(A, W, 768, br * 128, bc * 128, As, Bs, acc);

    const int t = threadIdx.x, l = t & 63, w = t >> 6;
    const int lr = l & 15, lg = l >> 4, wm = w >> 1, wn = w & 1;
    const int mrow0 = br * 128 + wm * 64 + lg * 4;
    const int ecolB = bc * 128 + wn * 64 + lr;

#pragma unroll
    for (int n = 0; n < 4; n++) {
        const int e = ecolB + n * 16;
        const float bv = bias[e];
#pragma unroll
        for (int m = 0; m < 4; m++) {
            const int mr = mrow0 + m * 16;
#pragma unroll
            for (int r = 0; r < 4; r++)
                out[(mr + r) * 768 + e] = acc[m][n][r] + bv;
        }
    }
}

// ---------------------------------------------------------------------------
extern "C" void kernel_launch(void* const* d_in, const int* in_sizes, int n_in,
                              void* d_out, int out_size, void* d_ws, size_t ws_size,
                              hipStream_t stream)
{
    const float* x  = (const float*)d_in[0];   // [8,1024,768] f32
    const float* wq = (const float*)d_in[1];   // [2304,768]   f32
    const float* wp = (const float*)d_in[2];   // [768,768]    f32
    const float* pb = (const float*)d_in[3];   // [768]        f32
    float* out = (float*)d_out;                // [8,1024,768] f32

    const int NX = 8 * 1024 * 768;             // 6291456
    const int NQ = 2304 * 768;                 // 1769472
    const int NP = 768 * 768;                  // 589824
    const int SEG = 8 * 12 * 1024 * 64;        // 6291456

    ushort* xb  = (ushort*)d_ws;               // x bf16; reused as ao after qkv
    ushort* wqb = xb + NX;
    ushort* wpb = wqb + NQ;
    ushort* qb  = wpb + NP;                    // q  [bh][n][64]  (pre-scaled)
    ushort* kb  = qb + SEG;                    // k  [bh][n][64]
    ushort* vb  = kb + SEG;                    // vT [bh][64][n]
    ushort* ao  = xb;                          // attn out aliases xb (dead by then)

    cvt_all<<<2048, 256, 0, stream>>>(x, wq, wp, xb, NX / 4, NQ / 4, NP / 4);

    qkv_gemm256<<<dim3(32, 9), 512, 0, stream>>>(xb, wqb, qb, kb, vb);
    attn_kernel<<<dim3(96, 8), 256, 0, stream>>>(qb, kb, vb, ao);
    proj_gemm <<<dim3(64, 6), 256, 0, stream>>>(ao, wpb, pb, out);
}

// Round 14
// 119.532 us; speedup vs baseline: 1.0995x; 1.0995x over previous
//
#include <hip/hip_runtime.h>

typedef unsigned short ushort;
typedef __attribute__((ext_vector_type(4)))  float  f32x4;
typedef __attribute__((ext_vector_type(16))) float  f32x16;
typedef __attribute__((ext_vector_type(8)))  short  s16x8;
typedef __attribute__((ext_vector_type(4)))  ushort u16x4;
typedef __attribute__((ext_vector_type(4)))  unsigned u32x4;

#define MFMA16(a, b, c) __builtin_amdgcn_mfma_f32_16x16x32_bf16((a), (b), (c), 0, 0, 0)
#define MFMA32(a, b, c) __builtin_amdgcn_mfma_f32_32x32x16_bf16((a), (b), (c), 0, 0, 0)

__device__ __forceinline__ ushort f2bf(float f) {
    unsigned u = __builtin_bit_cast(unsigned, f);
    u = (u + 0x7FFF + ((u >> 16) & 1)) >> 16;   // RNE
    return (ushort)u;
}

__device__ __forceinline__ unsigned cvtpk_bf16(float lo, float hi) {
    unsigned r;
    asm("v_cvt_pk_bf16_f32 %0, %1, %2" : "=v"(r) : "v"(lo), "v"(hi));
    return r;
}
// After the swap: a = [a_lo31 | b_lo31], b = [a_hi31 | b_hi31].
// Only safe when a and b are DISTINCT SSA values (regalloc coalescing hazard).
__device__ __forceinline__ void plswap(unsigned& a, unsigned& b) {
    asm volatile("v_permlane32_swap_b32 %0, %1" : "+v"(a), "+v"(b));
}
// Pair (lane ^ 32) reductions via permlane32_swap (pure VALU, no DS op).
__device__ __forceinline__ float pairmax(float x) {
    unsigned a = __builtin_bit_cast(unsigned, x), b;
    asm("v_mov_b32 %0, %1" : "=v"(b) : "v"(a));
    plswap(a, b);
    return fmaxf(__builtin_bit_cast(float, a), __builtin_bit_cast(float, b));
}
__device__ __forceinline__ float pairsum(float x) {
    unsigned a = __builtin_bit_cast(unsigned, x), b;
    asm("v_mov_b32 %0, %1" : "=v"(b) : "v"(a));
    plswap(a, b);
    return __builtin_bit_cast(float, a) + __builtin_bit_cast(float, b);
}
// Raw 2^x. exp() folded to exp2 via Q pre-scale by log2(e).
__device__ __forceinline__ float fast_exp2(float x) {
    float r;
    asm("v_exp_f32 %0, %1" : "=v"(r) : "v"(x));
    return r;
}

__device__ __forceinline__ void gload_lds16(const ushort* g, ushort* l) {
    __builtin_amdgcn_global_load_lds(
        (const __attribute__((address_space(1))) void*)g,
        (__attribute__((address_space(3))) void*)l, 16, 0, 0);
}

// ---------------------------------------------------------------------------
// fp32 -> bf16 conversion for all three inputs in ONE dispatch.
// ---------------------------------------------------------------------------
__global__ __launch_bounds__(256) void cvt_all(
    const float* __restrict__ x, const float* __restrict__ wq,
    const float* __restrict__ wp, ushort* __restrict__ out,
    int n4x, int n4q, int n4p)
{
    int i = blockIdx.x * blockDim.x + threadIdx.x;
    const int stride = gridDim.x * blockDim.x;
    const int total = n4x + n4q + n4p;
    for (; i < total; i += stride) {
        float4 v;
        if (i < n4x)            v = ((const float4*)x)[i];
        else if (i < n4x + n4q) v = ((const float4*)wq)[i - n4x];
        else                    v = ((const float4*)wp)[i - n4x - n4q];
        u16x4 o;
        o[0] = f2bf(v.x); o[1] = f2bf(v.y); o[2] = f2bf(v.z); o[3] = f2bf(v.w);
        ((u16x4*)out)[i] = o;
    }
}

// ---------------------------------------------------------------------------
// 128x128 tile GEMM mainloop, 3-buffer / 2-deep prefetch / counted vmcnt,
// slot-XOR bank swizzle (R11-verified). Used by qkv_gemm.
// ---------------------------------------------------------------------------
__device__ __forceinline__ void gemm128_mainloop(
    const ushort* __restrict__ A, const ushort* __restrict__ B, int K,
    int row0, int col0, ushort* As, ushort* Bs, f32x4 acc[4][4])
{
    const int t  = threadIdx.x;
    const int l  = t & 63;
    const int w  = t >> 6;
    const int lr = l & 15, lg = l >> 4;
    const int wm = w >> 1, wn = w & 1;

#pragma unroll
    for (int m = 0; m < 4; m++)
#pragma unroll
        for (int n = 0; n < 4; n++) acc[m][n] = (f32x4){0.f, 0.f, 0.f, 0.f};

    const int slot = (t & 3) ^ ((t >> 3) & 3);
    const ushort* ga0 = A + (row0 + (t >> 2)) * K + slot * 8;
    const ushort* gb0 = B + (col0 + (t >> 2)) * K + slot * 8;
    const int rowsz = 64 * K;
    ushort* la0 = As + t * 8;
    ushort* lb0 = Bs + t * 8;

    auto STAGE = [&](int kt, int buf) {
        const int k0  = kt * 32;
        const int off = buf * 4096;
        gload_lds16(ga0 + k0,         la0 + off);
        gload_lds16(ga0 + rowsz + k0, la0 + off + 2048);
        gload_lds16(gb0 + k0,         lb0 + off);
        gload_lds16(gb0 + rowsz + k0, lb0 + off + 2048);
    };
    const int sx = (lg ^ ((lr >> 1) & 3)) * 8;
    auto COMPUTE = [&](int buf) {
        const ushort* Ab = As + buf * 4096;
        const ushort* Bb = Bs + buf * 4096;
        s16x8 af[4], bfr[4];
#pragma unroll
        for (int m = 0; m < 4; m++)
            af[m] = *(const s16x8*)&Ab[(wm * 64 + m * 16 + lr) * 32 + sx];
#pragma unroll
        for (int n = 0; n < 4; n++)
            bfr[n] = *(const s16x8*)&Bb[(wn * 64 + n * 16 + lr) * 32 + sx];
        __builtin_amdgcn_s_setprio(1);
#pragma unroll
        for (int m = 0; m < 4; m++)
#pragma unroll
            for (int n = 0; n < 4; n++)
                acc[m][n] = MFMA16(af[m], bfr[n], acc[m][n]);
        __builtin_amdgcn_s_setprio(0);
    };

    const int nt = K >> 5;          // 24; must be divisible by 3
    STAGE(0, 0);
    STAGE(1, 1);
    asm volatile("s_waitcnt vmcnt(4)" ::: "memory");
    __builtin_amdgcn_s_barrier();

#define GSTEP(IT, CBUF, SBUF)                                          \
    {                                                                  \
        const int sk = (IT) + 2;                                       \
        const bool st = sk < nt;                                       \
        if (st) STAGE(sk, SBUF);                                       \
        COMPUTE(CBUF);                                                 \
        if (st) { asm volatile("s_waitcnt vmcnt(4)" ::: "memory"); }   \
        else    { asm volatile("s_waitcnt vmcnt(0)" ::: "memory"); }   \
        __builtin_amdgcn_s_barrier();                                  \
    }

    for (int base = 0; base < nt; base += 3) {
        GSTEP(base,     0, 2);
        GSTEP(base + 1, 1, 0);
        GSTEP(base + 2, 2, 1);
    }
#undef GSTEP
}

// ---------------------------------------------------------------------------
// Kernel 1: QKV = x @ qkv_w^T, scatter into q[bh][n][64] (pre-scaled by
// SCALE*log2e), k[bh][n][64], vT[bh][64][n].  grid (64, 18), block 256.
// (R11 version — the 8-phase 256^2 port regressed: 1 block/CU occupancy.)
// ---------------------------------------------------------------------------
__global__ __launch_bounds__(256) void qkv_gemm(
    const ushort* __restrict__ X, const ushort* __restrict__ W,
    ushort* __restrict__ qb, ushort* __restrict__ kb, ushort* __restrict__ vb)
{
    __shared__ __align__(16) ushort As[3 * 128 * 32];
    __shared__ __align__(16) ushort Bs[3 * 128 * 32];
    f32x4 acc[4][4];
    const int br = blockIdx.x, bc = blockIdx.y;
    gemm128_mainloop(X, W, 768, br * 128, bc * 128, As, Bs, acc);

    const int t = threadIdx.x, l = t & 63, w = t >> 6;
    const int lr = l & 15, lg = l >> 4, wm = w >> 1, wn = w & 1;
    const int p = (bc * 128) / 768;
    const int mrow0 = br * 128 + wm * 64 + lg * 4;
    const int ecolB = bc * 128 + wn * 64 + lr;
    const float QSCALE = 0.125f * 1.44269504088896f;  // SCALE * log2(e)

#pragma unroll
    for (int n = 0; n < 4; n++) {
        const int e   = ecolB + n * 16;
        const int rem = e - p * 768;
        const int h   = rem >> 6;
        const int hd  = rem & 63;
#pragma unroll
        for (int m = 0; m < 4; m++) {
            const int mr = mrow0 + m * 16;
            const int b  = mr >> 10;
            const int nn = mr & 1023;
            const f32x4 v = acc[m][n];
            const int bh = b * 12 + h;
            if (p == 0) {
                ushort* dst = qb + (bh * 1024 + nn) * 64 + hd;
#pragma unroll
                for (int r = 0; r < 4; r++) dst[r * 64] = f2bf(v[r] * QSCALE);
            } else if (p == 1) {
                ushort* dst = kb + (bh * 1024 + nn) * 64 + hd;
#pragma unroll
                for (int r = 0; r < 4; r++) dst[r * 64] = f2bf(v[r]);
            } else {
                u16x4 pk;
                pk[0] = f2bf(v[0]); pk[1] = f2bf(v[1]);
                pk[2] = f2bf(v[2]); pk[3] = f2bf(v[3]);
                *(u16x4*)(vb + (bh * 64 + hd) * 1024 + nn) = pk;
            }
        }
    }
}

// ---------------------------------------------------------------------------
// Kernel 2: flash attention. R11 structure, but K/V staging upgraded to the
// 3-buffer / 2-deep prefetch / counted-vmcnt schedule (GEMM-proven, R8):
// stage tile it+2 at iteration top; end-of-iter waits vmcnt(2) — the newest
// stage's 2 loads stay in flight, giving each a 2-iteration latency window.
// grid (96 bh, 8 qt), block 256 = 4 waves. LDS 3 x 8KB = 24KB.
// ---------------------------------------------------------------------------
__global__ __launch_bounds__(256) void attn_kernel(
    const ushort* __restrict__ qb, const ushort* __restrict__ kb,
    const ushort* __restrict__ vb, ushort* __restrict__ ao)
{
    __shared__ __align__(16) ushort KV[3][4096];   // [buf][K 2048 | V 2048]
    const int bh = blockIdx.x, qt = blockIdx.y;
    const int b = bh / 12, h = bh - b * 12;
    const int t = threadIdx.x, l = t & 63, w = t >> 6;
    const int lq = l & 31, hi = l >> 5;
    const int qr0 = qt * 128 + w * 32;

    // ---- staging source addresses (pre-swizzled) ----
    const int l3 = l >> 3, l7 = l & 7;
    const int ku = w * 8 + l3;                      // LDS row this lane fills
    const int pfv = l7 ^ l3;                        // swizzled 16B slot index
    const char* ksrc = (const char*)kb + (size_t)(bh * 1024 + ku) * 128
                     + ((l7 ^ l3) << 4);            // + kv0*128 per tile
    const char* vsrc = (const char*)vb + (size_t)(bh * 64 + ku + 32 * ((pfv >> 2) & 1)) * 2048
                     + ((pfv & 3) << 4);            // + kv0*2 per tile
    ushort* kdst = &KV[0][0]    + t * 8;            // uniform base + lane*16B
    ushort* vdst = &KV[0][2048] + t * 8;

    auto STAGE = [&](int kt, int buf) {
        gload_lds16((const ushort*)(ksrc + kt * 32 * 128), kdst + buf * 4096);
        gload_lds16((const ushort*)(vsrc + kt * 32 * 2),   vdst + buf * 4096);
    };

    // ---- Q fragments (B-operand): col=q=lq, k=d-slice s*16 + hi*8 ----
    const ushort* qlane = qb + (bh * 1024 + qr0 + lq) * 64 + hi * 8;
    s16x8 qf[4];
#pragma unroll
    for (int s = 0; s < 4; s++) qf[s] = *(const s16x8*)(qlane + s * 16);

    float m = -__builtin_inff();
    float lsum = 0.f;
    f32x16 o0 = {}, o1 = {};

    // prologue: tiles 0,1 in flight
    STAGE(0, 0);
    STAGE(1, 1);
    asm volatile("s_waitcnt vmcnt(2)" ::: "memory");   // tile0 landed
    __builtin_amdgcn_s_barrier();

    const int fx = (lq & 7) << 4;                   // read-side swizzle
    int cur = 0;
    for (int it = 0; it < 32; ++it) {
        const bool st = it < 30;
        if (st) {
            int sb = cur + 2; if (sb >= 3) sb -= 3;
            STAGE(it + 2, sb);
        }
        const char* Kb = (const char*)&KV[cur][0];
        const char* Vb = (const char*)&KV[cur][2048];

        // ---- K fragments (A-operand): row kv=lq, d-slice s*16+hi*8 ----
        s16x8 kf[4];
#pragma unroll
        for (int s = 0; s < 4; s++)
            kf[s] = *(const s16x8*)(Kb + lq * 128 + ((hi * 16 + s * 32) ^ fx));

        f32x16 sa = {};
        __builtin_amdgcn_s_setprio(1);
#pragma unroll
        for (int s = 0; s < 4; s++) sa = MFMA32(kf[s], qf[s], sa);
        __builtin_amdgcn_s_setprio(0);

        // ---- in-register online softmax (16 k/lane, pair lane has rest) ----
        float g0 = fmaxf(fmaxf(sa[0],  sa[1]),  sa[2]);
        float g1 = fmaxf(fmaxf(sa[3],  sa[4]),  sa[5]);
        float g2 = fmaxf(fmaxf(sa[6],  sa[7]),  sa[8]);
        float g3 = fmaxf(fmaxf(sa[9],  sa[10]), sa[11]);
        float g4 = fmaxf(fmaxf(sa[12], sa[13]), sa[14]);
        float h0 = fmaxf(fmaxf(g0, g1), g2);
        float h1 = fmaxf(fmaxf(g3, g4), sa[15]);
        const float mx = pairmax(fmaxf(h0, h1));

        if (!__all(mx <= m + 8.f)) {          // defer-max (T13), log2 units
            const float mn = fmaxf(m, mx);
            const float fac = fast_exp2(m - mn);
            m = mn;
            lsum *= fac;
#pragma unroll
            for (int r = 0; r < 16; r++) { o0[r] *= fac; o1[r] *= fac; }
        }

        float p[16];
#pragma unroll
        for (int r = 0; r < 16; r++) p[r] = fast_exp2(sa[r] - m);
        float ts[8];
#pragma unroll
        for (int r = 0; r < 8; r++) ts[r] = p[r] + p[r + 8];
#pragma unroll
        for (int s = 4; s; s >>= 1)
#pragma unroll
            for (int r = 0; r < s; r++) ts[r] += ts[r + s];
        lsum += pairsum(ts[0]);

        // ---- pack P^T into PV B-fragments (cvt_pk + permlane32_swap) ----
        s16x8 pfr[2];
#pragma unroll
        for (int slot = 0; slot < 2; slot++) {
            const int r0 = slot * 8;
            unsigned a0 = cvtpk_bf16(p[r0 + 0], p[r0 + 1]);
            unsigned a1 = cvtpk_bf16(p[r0 + 4], p[r0 + 5]);
            plswap(a0, a1);
            unsigned b0 = cvtpk_bf16(p[r0 + 2], p[r0 + 3]);
            unsigned b1 = cvtpk_bf16(p[r0 + 6], p[r0 + 7]);
            plswap(b0, b1);
            const u32x4 u = {a0, b0, a1, b1};
            pfr[slot] = __builtin_bit_cast(s16x8, u);
        }

        // ---- V fragments + PV: O^T += V^T * P^T ----
        s16x8 vf[2][2];   // [half d0/d32][k-slot]
#pragma unroll
        for (int half = 0; half < 2; half++)
#pragma unroll
            for (int s = 0; s < 2; s++)
                vf[half][s] = *(const s16x8*)(Vb + lq * 128 + ((half * 64 + hi * 16 + s * 32) ^ fx));
        __builtin_amdgcn_s_setprio(1);
        o0 = MFMA32(vf[0][0], pfr[0], o0);
        o1 = MFMA32(vf[1][0], pfr[0], o1);
        o0 = MFMA32(vf[0][1], pfr[1], o0);
        o1 = MFMA32(vf[1][1], pfr[1], o1);
        __builtin_amdgcn_s_setprio(0);

        if (st) { asm volatile("s_waitcnt vmcnt(2)" ::: "memory"); }
        else    { asm volatile("s_waitcnt vmcnt(0)" ::: "memory"); }
        __builtin_amdgcn_s_barrier();
        cur = (cur == 2) ? 0 : cur + 1;
    }

    // ---- epilogue: out[b][q][h*64+d] = O^T[d][q] / lsum ----
    const float inv = 1.f / lsum;
    ushort* op = ao + (b * 1024 + qr0 + lq) * 768 + h * 64 + 4 * hi;
#pragma unroll
    for (int i = 0; i < 4; i++) {
        u16x4 pk0, pk1;
#pragma unroll
        for (int j = 0; j < 4; j++) {
            pk0[j] = f2bf(o0[4 * i + j] * inv);
            pk1[j] = f2bf(o1[4 * i + j] * inv);
        }
        *(u16x4*)(op + 8 * i)      = pk0;   // d = 8i+4hi + 0..3
        *(u16x4*)(op + 32 + 8 * i) = pk1;   // d = 32 + 8i+4hi + 0..3
    }
}

// ---------------------------------------------------------------------------
// Kernel 3: out = attn_out @ proj_w^T + proj_b (fp32 out).
// 64x128 tile for 2x block parallelism (grid (128,6) = 768 blocks = exactly
// the 3-blocks/CU residency). Same 3-buffer / vmcnt(3) schedule; per-wave
// 32x64 = acc[2][4]; STAGE = 3 gload_lds. LDS 3 x 12KB = 36KB.
// ---------------------------------------------------------------------------
__global__ __launch_bounds__(256) void proj_gemm(
    const ushort* __restrict__ A, const ushort* __restrict__ W,
    const float* __restrict__ bias, float* __restrict__ out)
{
    __shared__ __align__(16) ushort As[3 * 64 * 32];
    __shared__ __align__(16) ushort Bs[3 * 128 * 32];
    const int t = threadIdx.x, l = t & 63, w = t >> 6;
    const int lr = l & 15, lg = l >> 4;
    const int wm = w >> 1, wn = w & 1;
    const int br = blockIdx.x, bc = blockIdx.y;

    f32x4 acc[2][4];
#pragma unroll
    for (int m = 0; m < 2; m++)
#pragma unroll
        for (int n = 0; n < 4; n++) acc[m][n] = (f32x4){0.f, 0.f, 0.f, 0.f};

    const int slot = (t & 3) ^ ((t >> 3) & 3);
    const ushort* ga0 = A + (br * 64 + (t >> 2)) * 768 + slot * 8;
    const ushort* gb0 = W + (bc * 128 + (t >> 2)) * 768 + slot * 8;
    ushort* la0 = As + t * 8;
    ushort* lb0 = Bs + t * 8;

    auto STAGE = [&](int kt, int buf) {
        const int k0 = kt * 32;
        gload_lds16(ga0 + k0,            la0 + buf * 2048);
        gload_lds16(gb0 + k0,            lb0 + buf * 4096);
        gload_lds16(gb0 + 64 * 768 + k0, lb0 + buf * 4096 + 2048);
    };
    const int sx = (lg ^ ((lr >> 1) & 3)) * 8;
    auto COMPUTE = [&](int buf) {
        const ushort* Ab = As + buf * 2048;
        const ushort* Bb = Bs + buf * 4096;
        s16x8 af[2], bfr[4];
#pragma unroll
        for (int m = 0; m < 2; m++)
            af[m] = *(const s16x8*)&Ab[(wm * 32 + m * 16 + lr) * 32 + sx];
#pragma unroll
        for (int n = 0; n < 4; n++)
            bfr[n] = *(const s16x8*)&Bb[(wn * 64 + n * 16 + lr) * 32 + sx];
        __builtin_amdgcn_s_setprio(1);
#pragma unroll
        for (int m = 0; m < 2; m++)
#pragma unroll
            for (int n = 0; n < 4; n++)
                acc[m][n] = MFMA16(af[m], bfr[n], acc[m][n]);
        __builtin_amdgcn_s_setprio(0);
    };

    const int nt = 24;
    STAGE(0, 0);
    STAGE(1, 1);
    asm volatile("s_waitcnt vmcnt(3)" ::: "memory");
    __builtin_amdgcn_s_barrier();

#define GSTEP(IT, CBUF, SBUF)                                          \
    {                                                                  \
        const int sk = (IT) + 2;                                       \
        const bool st = sk < nt;                                       \
        if (st) STAGE(sk, SBUF);                                       \
        COMPUTE(CBUF);                                                 \
        if (st) { asm volatile("s_waitcnt vmcnt(3)" ::: "memory"); }   \
        else    { asm volatile("s_waitcnt vmcnt(0)" ::: "memory"); }   \
        __builtin_amdgcn_s_barrier();                                  \
    }

    for (int base = 0; base < nt; base += 3) {
        GSTEP(base,     0, 2);
        GSTEP(base + 1, 1, 0);
        GSTEP(base + 2, 2, 1);
    }
#undef GSTEP

    const int mrow0 = br * 64 + wm * 32 + lg * 4;
    const int ecolB = bc * 128 + wn * 64 + lr;
#pragma unroll
    for (int n = 0; n < 4; n++) {
        const int e = ecolB + n * 16;
        const float bv = bias[e];
#pragma unroll
        for (int m = 0; m < 2; m++) {
            const int mr = mrow0 + m * 16;
#pragma unroll
            for (int r = 0; r < 4; r++)
                out[(mr + r) * 768 + e] = acc[m][n][r] + bv;
        }
    }
}

// ---------------------------------------------------------------------------
extern "C" void kernel_launch(void* const* d_in, const int* in_sizes, int n_in,
                              void* d_out, int out_size, void* d_ws, size_t ws_size,
                              hipStream_t stream)
{
    const float* x  = (const float*)d_in[0];   // [8,1024,768] f32
    const float* wq = (const float*)d_in[1];   // [2304,768]   f32
    const float* wp = (const float*)d_in[2];   // [768,768]    f32
    const float* pb = (const float*)d_in[3];   // [768]        f32
    float* out = (float*)d_out;                // [8,1024,768] f32

    const int NX = 8 * 1024 * 768;             // 6291456
    const int NQ = 2304 * 768;                 // 1769472
    const int NP = 768 * 768;                  // 589824
    const int SEG = 8 * 12 * 1024 * 64;        // 6291456

    ushort* xb  = (ushort*)d_ws;               // x bf16; reused as ao after qkv
    ushort* wqb = xb + NX;
    ushort* wpb = wqb + NQ;
    ushort* qb  = wpb + NP;                    // q  [bh][n][64]  (pre-scaled)
    ushort* kb  = qb + SEG;                    // k  [bh][n][64]
    ushort* vb  = kb + SEG;                    // vT [bh][64][n]
    ushort* ao  = xb;                          // attn out aliases xb (dead by then)

    cvt_all<<<2048, 256, 0, stream>>>(x, wq, wp, xb, NX / 4, NQ / 4, NP / 4);

    qkv_gemm  <<<dim3(64, 18), 256, 0, stream>>>(xb, wqb, qb, kb, vb);
    attn_kernel<<<dim3(96, 8), 256, 0, stream>>>(qb, kb, vb, ao);
    proj_gemm <<<dim3(128, 6), 256, 0, stream>>>(ao, wpb, pb, out);
}